// Round 9
// baseline (829.965 us; speedup 1.0000x reference)
//
#include <hip/hip_runtime.h>
#include <math.h>

// ---------------------------------------------------------------------------
// GTR_50139448214076: 3x TransformerConv GNN + BN/ELU + mean-pool + MLP
// All GEMMs MFMA fp16, activations fp16, fp32 acc.
// R9: BK=64 K-step (one barrier pair / 64 K, bank-exact XOR-8 swizzle);
//     MLP head stages weights in LDS (kills 110us latency-bound dispatch).
// ---------------------------------------------------------------------------

typedef _Float16 f16;
typedef _Float16 half8  __attribute__((ext_vector_type(8)));
typedef _Float16 half4v __attribute__((ext_vector_type(4)));
typedef float    f32x4  __attribute__((ext_vector_type(4)));

__device__ __forceinline__ void gload16(const void* g, void* l){
  __builtin_amdgcn_global_load_lds((const __attribute__((address_space(1))) void*)g,
                                   (__attribute__((address_space(3))) void*)l, 16, 0, 0);
}

// ---------------- utility ----------------
__global__ void leak_kernel(float* __restrict__ out, int n, float val){
  int i = blockIdx.x*blockDim.x + threadIdx.x;
  if (i < n) out[i] = val;
}

// ---------------- CSR build ----------------
__global__ void hist_kernel(const int* __restrict__ dst, int* __restrict__ deg, int E){
  int i = blockIdx.x*blockDim.x + threadIdx.x;
  if (i < E) atomicAdd(&deg[dst[i]], 1);
}

__global__ __launch_bounds__(1024)
void scan_kernel(const int* __restrict__ deg, int* __restrict__ rowptr, int n){
  __shared__ int buf[1024];
  __shared__ int sbase;
  int tid = threadIdx.x;
  if (tid == 0){ sbase = 0; rowptr[0] = 0; }
  __syncthreads();
  for (int start = 0; start < n; start += 4096){
    int i0 = start + tid*4;
    int a0 = (i0+0<n)?deg[i0+0]:0;
    int a1 = (i0+1<n)?deg[i0+1]:0;
    int a2 = (i0+2<n)?deg[i0+2]:0;
    int a3 = (i0+3<n)?deg[i0+3]:0;
    int s = a0+a1+a2+a3;
    int v = s;
    buf[tid] = v;
    __syncthreads();
    for (int off=1; off<1024; off<<=1){
      int t = (tid >= off) ? buf[tid-off] : 0;
      __syncthreads();
      v += t;
      buf[tid] = v;
      __syncthreads();
    }
    int pre = sbase + v - s;
    if (i0+0 < n) rowptr[i0+1] = pre + a0;
    if (i0+1 < n) rowptr[i0+2] = pre + a0 + a1;
    if (i0+2 < n) rowptr[i0+3] = pre + a0 + a1 + a2;
    if (i0+3 < n) rowptr[i0+4] = pre + s;
    __syncthreads();
    if (tid == 1023) sbase += buf[1023];
    __syncthreads();
  }
}

__global__ void scatter_kernel(const int* __restrict__ src, const int* __restrict__ dst,
                               const int* __restrict__ rowptr, int* __restrict__ cnt,
                               int* __restrict__ csr_src, int* __restrict__ csr_eid, int E){
  int i = blockIdx.x*blockDim.x + threadIdx.x;
  if (i >= E) return;
  int d = dst[i];
  int pos = rowptr[d] + atomicAdd(&cnt[d], 1);
  csr_src[pos] = src[i];
  csr_eid[pos] = i;
}

// EFh[i] = EFt[csr_eid[i]]  (fp16 edge features -> CSR order)
__global__ void gather_ef16_kernel(const f16* __restrict__ EFt, const int* __restrict__ csr_eid,
                                   f16* __restrict__ EFh, int E){
  int i = blockIdx.x*blockDim.x + threadIdx.x;   // E*8 chunks of 8 halves
  if (i >= E*8) return;
  int e = i >> 3, j8 = (i & 7) * 8;
  *(half8*)(EFh + (size_t)e*64 + j8) = *(const half8*)(EFt + (size_t)csr_eid[e]*64 + j8);
}

// ---------------- unified prep: weight pack + bias + zero + cvt ----------------
// Bpk layout (halves), B^T [col][Kp]:
//  [0,2048)        enc1: 64 x 32  (ee_w1, K=16 zero-padded)
//  [2048,6144)     enc2: 64 x 64
//  [6144,71680)    proj0: 1024 x 64   [wq|wk|wv|wqe]
//  [71680,333824)  proj1: 1024 x 256
//  [333824,399360) proj2: 256 x 256
//  [399360,432128) post0: 256 x 128   [we(compact);ws], Kpp=64+din
//  [432128,514048) post1: 256 x 320
//  [514048,534528) post2: 64 x 320
// biasAll (fp32): [0,1024) conv0 [bq|bk|bv|bqe]; [1024,2048) conv1; [2048,2304) conv2
struct PrepP {
  const float *ee_w1, *ee_w2;
  const float *wq[3], *wk[3], *wv[3], *we[3], *ws[3];
  const float *bq[3], *bk[3], *bv[3];
  f16* Bpk; float* biasAll;
  int* zeroP; int nZero;
  const float* eattr; f16* EA16; int nEA;
  const float* x; f16* XA; int nXA;
};

__device__ __forceinline__ float projv(const float* wq, const float* wk, const float* wv,
                                       const float* we, int hc, int din, int x){
  int c = x / din, k = x - c*din;
  int sec = c / hc, cc = c - sec*hc;
  if (sec == 0) return wq[(size_t)k*hc + cc];
  if (sec == 1) return wk[(size_t)k*hc + cc];
  if (sec == 2) return wv[(size_t)k*hc + cc];
  int h = cc >> 6, jj = cc & 63;
  const float* q = wq + (size_t)k*hc + h*64;
  const float* w = we + (size_t)jj*hc + h*64;
  float s = 0.f;
  #pragma unroll 8
  for (int t = 0; t < 64; ++t) s += q[t]*w[t];
  return s;
}
__device__ __forceinline__ float postv(const float* we, const float* ws,
                                       int hc, int din, int x){
  int Kpp = 64 + din;
  int c = x / Kpp, k = x - c*Kpp;
  if (k < 64) return we[(size_t)k*hc + c];
  return ws[(size_t)(k-64)*hc + c];
}

__global__ void prep_kernel(PrepP P){
  int id = blockIdx.x*blockDim.x + threadIdx.x;
  const int NB = 534528, NBB = NB + 2304;
  if (id < NB){
    float v;
    if      (id < 2048)  { int c = id>>5, k = id&31; v = (k<16) ? P.ee_w1[k*64 + c] : 0.f; }
    else if (id < 6144)  { int x = id-2048; int c = x>>6, k = x&63; v = P.ee_w2[k*64 + c]; }
    else if (id < 71680) v = projv(P.wq[0],P.wk[0],P.wv[0],P.we[0],256,64, id-6144);
    else if (id < 333824)v = projv(P.wq[1],P.wk[1],P.wv[1],P.we[1],256,256,id-71680);
    else if (id < 399360)v = projv(P.wq[2],P.wk[2],P.wv[2],P.we[2],64, 256,id-333824);
    else if (id < 432128)v = postv(P.we[0],P.ws[0],256,64, id-399360);
    else if (id < 514048)v = postv(P.we[1],P.ws[1],256,256,id-432128);
    else                 v = postv(P.we[2],P.ws[2],64, 256,id-514048);
    P.Bpk[id] = (f16)v;
  } else if (id < NBB){
    int x = id - NB;
    int cv, off, hc;
    if (x < 1024){ cv = 0; off = x;        hc = 256; }
    else if (x < 2048){ cv = 1; off = x-1024; hc = 256; }
    else { cv = 2; off = x-2048; hc = 64; }
    int sec = off / hc, cc = off - sec*hc;
    float v;
    if      (sec == 0) v = P.bq[cv][cc];
    else if (sec == 1) v = P.bk[cv][cc];
    else if (sec == 2) v = P.bv[cv][cc];
    else {
      int h = cc >> 6, jj = cc & 63;
      const float* b = P.bq[cv] + h*64;
      const float* w = P.we[cv] + (size_t)jj*hc + h*64;
      v = 0.f;
      #pragma unroll 8
      for (int t = 0; t < 64; ++t) v += b[t]*w[t];
    }
    P.biasAll[x] = v;
  } else if (id < NBB + P.nZero){
    P.zeroP[id - NBB] = 0;
  } else if (id < NBB + P.nZero + P.nEA){
    int i = id - NBB - P.nZero;
    P.EA16[i] = (f16)P.eattr[i];
  } else if (id < NBB + P.nZero + P.nEA + P.nXA){
    int i = id - NBB - P.nZero - P.nEA;
    P.XA[i] = (f16)P.x[i];
  }
}

// ---------------- MFMA fp16 GEMM (gload_lds + XOR swizzle, 128xBN, BK) ------
// C = [A1 | A2] @ Bpk + bias.  Grid (Ncols/BN, ceil(M/128)).
// LDS slot (row r, chunk c):
//   BK=64: holds global chunk c ^ (r&7)       (row stride 128B = bank-exact)
//   BK=32: holds global chunk c ^ ((r>>2)&3)
// headOff: A1 += col0 (post GEMM per-head SE slice).
// pstride!=0: plane-split C write.
// mode 0: +bias; 1: +bias,relu; 2: +bias +ep(f16,ldep) +BN +ELU.
__device__ __forceinline__ float bn_elu(float x, float g, float b, float m, float v){
  float s = g / sqrtf(v + 1e-5f);
  float y = (x - m) * s + b;
  return y > 0.f ? y : expm1f(y);
}

template<int BN, int BK>
__global__ __launch_bounds__(256)
void hgemm_kernel(const f16* __restrict__ A1, int lda1, int K1,
                  const f16* __restrict__ A2, int lda2, int K2,
                  const f16* __restrict__ Bpk, int Kp,
                  const float* __restrict__ bias,
                  f16* __restrict__ C, int ldc, int M, int mode,
                  const f16* __restrict__ ep, int ldep,
                  const float* __restrict__ bng, const float* __restrict__ bnb,
                  const float* __restrict__ bnm, const float* __restrict__ bnv,
                  int headOff, size_t pstride, int hcShift)
{
  constexpr int WM  = (BN == 128) ? 64 : 32;
  constexpr int MF  = WM / 16;
  constexpr int SUB = BK / 32;          // MFMA sub-steps per K-step
  constexpr int RPI = (BK == 64) ? 8 : 16;   // rows per gload issue
  __shared__ f16 As[128*BK];
  __shared__ f16 Bs[BN*BK];
  const int tid  = threadIdx.x;
  const int lane = tid & 63;
  const int wave = tid >> 6;
  const int wm   = (BN == 128) ? (wave >> 1) : wave;
  const int wn   = (BN == 128) ? (wave & 1) : 0;
  const int l15  = lane & 15;
  const int qw   = lane >> 4;
  const int arow = (BK == 64) ? (lane >> 3) : (lane >> 2);
  const int csl  = (BK == 64) ? ((lane & 7) ^ ((lane >> 3) & 7))
                              : ((lane & 3) ^ ((lane >> 4) & 3));

  // XCD-chunked bijective swizzle
  const int nbx = gridDim.x;
  const int nwg = nbx * gridDim.y;
  int bid = blockIdx.y * nbx + blockIdx.x;
  {
    int q = nwg >> 3, r = nwg & 7;
    int xcd = bid & 7, idx = bid >> 3;
    bid = (xcd < r ? xcd * (q + 1) : r * (q + 1) + (xcd - r) * q) + idx;
  }
  const int row0 = (bid / nbx) * 128;
  const int col0 = (bid % nbx) * BN;
  const f16* A1b = headOff ? (A1 + col0) : A1;

  f32x4 acc[MF*4];
  #pragma unroll
  for (int i = 0; i < MF*4; ++i){ acc[i][0]=0.f; acc[i][1]=0.f; acc[i][2]=0.f; acc[i][3]=0.f; }

  for (int k0 = 0; k0 < Kp; k0 += BK) {
    const f16* Ap; int lda, ks;
    if (k0 < K1) { Ap = A1b; lda = lda1; ks = k0; }
    else         { Ap = A2;  lda = lda2; ks = k0 - K1; }
    // stage A: wave covers rows [wave*32, wave*32+32)
    #pragma unroll
    for (int t = 0; t < 32/RPI; ++t) {
      int r = wave*32 + t*RPI + arow;
      gload16(Ap + (size_t)(row0 + r)*lda + ks + csl*8, As + (wave*32 + t*RPI)*BK);
    }
    // stage B
    if (BN == 128) {
      #pragma unroll
      for (int t = 0; t < 32/RPI; ++t) {
        int r = wave*32 + t*RPI + arow;
        gload16(Bpk + (size_t)(col0 + r)*Kp + k0 + csl*8, Bs + (wave*32 + t*RPI)*BK);
      }
    } else {
      #pragma unroll
      for (int t = 0; t < 16/RPI; ++t) {
        int r = wave*16 + t*RPI + arow;
        gload16(Bpk + (size_t)(col0 + r)*Kp + k0 + csl*8, Bs + (wave*16 + t*RPI)*BK);
      }
    }
    __syncthreads();   // drains vmcnt (compiler emits s_waitcnt vmcnt(0))

    #pragma unroll
    for (int s = 0; s < SUB; ++s) {
      int cfA;
      if (BK == 64) cfA = (s*4 + qw) ^ (l15 & 7);
      else          cfA = qw ^ ((l15 >> 2) & 3);
      half8 af[MF], bf[4];
      #pragma unroll
      for (int mf = 0; mf < MF; ++mf)
        af[mf] = *(const half8*)(As + (wm*WM + mf*16 + l15)*BK + cfA*8);
      #pragma unroll
      for (int nf = 0; nf < 4; ++nf)
        bf[nf] = *(const half8*)(Bs + (wn*64 + nf*16 + l15)*BK + cfA*8);
      #pragma unroll
      for (int mf = 0; mf < MF; ++mf)
        #pragma unroll
        for (int nf = 0; nf < 4; ++nf)
          acc[mf*4+nf] = __builtin_amdgcn_mfma_f32_16x16x32_f16(af[mf], bf[nf], acc[mf*4+nf], 0,0,0);
    }
    __syncthreads();
  }

  // epilogue: C/D layout col=lane&15, row=(lane>>4)*4+reg
  #pragma unroll
  for (int mf = 0; mf < MF; ++mf)
    #pragma unroll
    for (int nf = 0; nf < 4; ++nf){
      int col  = col0 + wn*64 + nf*16 + l15;
      int rowb = row0 + wm*WM + mf*16 + (lane>>4)*4;
      float bi = bias ? bias[col] : 0.f;
      #pragma unroll
      for (int i = 0; i < 4; ++i){
        int row = rowb + i;
        if (row >= M) continue;
        float r = acc[mf*4+nf][i] + bi;
        if (mode == 1) r = fmaxf(r, 0.f);
        else if (mode == 2){
          r += (float)ep[(size_t)row*ldep + col];
          r = bn_elu(r, bng[col], bnb[col], bnm[col], bnv[col]);
        }
        if (pstride){
          int hc = 1 << hcShift;
          int plane = col >> hcShift, c2 = col & (hc - 1);
          C[(size_t)plane*pstride + (size_t)row*hc + c2] = (f16)r;
        } else {
          C[(size_t)row*ldc + col] = (f16)r;
        }
      }
    }
}

// ---------------- aggregation: online softmax, 2-deep pipelined -------------
// Planes: Q=PROJ, K=PROJ+ps, V=+2ps, QWE=+3ps; each [N,HC] compact.
// att overwrites Q plane row, SE overwrites QWE plane row.
template<int HC>
__global__ __launch_bounds__(256)
void agg16_kernel(const int* __restrict__ rowptr, const int* __restrict__ csr_src,
                  f16* __restrict__ PROJ, size_t ps, const f16* __restrict__ EFh, int nNodes)
{
  int lane = threadIdx.x & 63;
  int wid = (blockIdx.x * blockDim.x + threadIdx.x) >> 6;
  int grp = lane >> 4, l16 = lane & 15;
  int node, ch;
  if (HC == 256) { node = wid;          ch = 4*lane; }
  else           { node = wid*4 + grp;  ch = 4*l16;  }
  if (node >= nNodes) return;
  f16* Qp = PROJ;
  const f16* Kp = PROJ + ps;
  const f16* Vp = PROJ + 2*ps;
  f16* Wp = PROJ + 3*ps;
  half4v qh = *(const half4v*)(Qp + (size_t)node*HC + ch);
  half4v wh = *(const half4v*)(Wp + (size_t)node*HC + ch);
  float q0=qh[0],q1=qh[1],q2=qh[2],q3=qh[3];
  float w0=wh[0],w1=wh[1],w2=wh[2],w3=wh[3];
  int e0 = rowptr[node], e1 = rowptr[node+1];

  float m = -INFINITY, den = 0.f;
  float avx=0.f,avy=0.f,avz=0.f,avw=0.f, aex=0.f,aey=0.f,aez=0.f,aew=0.f;

  half4v kN, vN, eN;
  if (e0 < e1) {
    size_t so = (size_t)csr_src[e0]*HC + ch;
    kN = *(const half4v*)(Kp + so);
    vN = *(const half4v*)(Vp + so);
    eN = *(const half4v*)(EFh + (size_t)e0*64 + 4*l16);
  }
  for (int i = e0; i < e1; ++i) {
    half4v k4 = kN, v4 = vN, e4 = eN;
    if (i + 1 < e1) {
      size_t so = (size_t)csr_src[i+1]*HC + ch;
      kN = *(const half4v*)(Kp + so);
      vN = *(const half4v*)(Vp + so);
      eN = *(const half4v*)(EFh + (size_t)(i+1)*64 + 4*l16);
    }
    float ex=e4[0], ey=e4[1], ez=e4[2], ew=e4[3];
    float p = q0*(float)k4[0] + q1*(float)k4[1] + q2*(float)k4[2] + q3*(float)k4[3]
            + w0*ex + w1*ey + w2*ez + w3*ew;
    p += __shfl_xor(p, 1);
    p += __shfl_xor(p, 2);
    p += __shfl_xor(p, 4);
    p += __shfl_xor(p, 8);
    float alpha = p * 0.125f;       // 1/sqrt(64)
    float mn = fmaxf(m, alpha);
    float sc = __expf(m - mn);      // -inf -> 0 on first edge
    float w  = __expf(alpha - mn);
    den = den*sc + w;
    avx = avx*sc + w*(float)v4[0]; avy = avy*sc + w*(float)v4[1];
    avz = avz*sc + w*(float)v4[2]; avw = avw*sc + w*(float)v4[3];
    aex = aex*sc + w*ex; aey = aey*sc + w*ey;
    aez = aez*sc + w*ez; aew = aew*sc + w*ew;
    m = mn;
  }
  float inv = den > 0.f ? 1.0f/den : 0.f;
  half4v o1, o2;
  o1[0]=(f16)(avx*inv); o1[1]=(f16)(avy*inv); o1[2]=(f16)(avz*inv); o1[3]=(f16)(avw*inv);
  o2[0]=(f16)(aex*inv); o2[1]=(f16)(aey*inv); o2[2]=(f16)(aez*inv); o2[3]=(f16)(aew*inv);
  *(half4v*)(Qp + (size_t)node*HC + ch) = o1;
  *(half4v*)(Wp + (size_t)node*HC + ch) = o2;
}

// ---------------- mean pool (batch sorted, fp16 in) ----------------
__global__ void pool16_kernel(const f16* __restrict__ Hf, const int* __restrict__ batch,
                              float* __restrict__ gsum, int nNodes){
  const int CH = 64;
  int c = threadIdx.x & 63;
  int chunk = blockIdx.x * (blockDim.x >> 6) + (threadIdx.x >> 6);
  int n0 = chunk * CH;
  if (n0 >= nNodes) return;
  int n1 = min(n0 + CH, nNodes);
  float acc = 0.f;
  int g = batch[n0];
  for (int n = n0; n < n1; ++n) {
    int gn = batch[n];
    if (gn != g) { atomicAdd(&gsum[g*64 + c], acc); acc = 0.f; g = gn; }
    acc += (float)Hf[(size_t)n*64 + c];
  }
  atomicAdd(&gsum[g*64 + c], acc);
}

// ---------------- MLP head: weights staged in LDS (fp32) ----------------
__global__ void mlp_kernel(const float* __restrict__ gsum, const int* __restrict__ batch,
                           int nNodes, int G,
                           const float* __restrict__ w1, const float* __restrict__ b1,
                           const float* __restrict__ w2, const float* __restrict__ b2,
                           const float* __restrict__ w3, const float* __restrict__ b3,
                           float* __restrict__ out){
  __shared__ float s_w1[2048], s_w2[512], s_w3[16], s_b1[32], s_b2[16];
  int t = threadIdx.x;
  for (int i = t; i < 2048; i += 128) s_w1[i] = w1[i];
  for (int i = t; i < 512;  i += 128) s_w2[i] = w2[i];
  if (t < 16) s_w3[t] = w3[t];
  if (t < 32) s_b1[t] = b1[t];
  if (t < 16) s_b2[t] = b2[t];
  __syncthreads();
  int g = t;
  if (g >= G) return;
  int lo = 0, hi = nNodes;
  while (lo < hi){ int mid = (lo+hi)>>1; if (batch[mid] < g) lo = mid+1; else hi = mid; }
  int first = lo;
  lo = 0; hi = nNodes;
  while (lo < hi){ int mid = (lo+hi)>>1; if (batch[mid] < g+1) lo = mid+1; else hi = mid; }
  int cnt = lo - first;
  float invc = 1.0f / fmaxf((float)cnt, 1.0f);
  float gm[64];
  #pragma unroll
  for (int c = 0; c < 64; ++c) gm[c] = gsum[g*64 + c] * invc;
  float r1[32];
  #pragma unroll
  for (int j = 0; j < 32; ++j){
    float s = s_b1[j];
    #pragma unroll 8
    for (int c = 0; c < 64; ++c) s = fmaf(gm[c], s_w1[c*32 + j], s);
    r1[j] = fmaxf(s, 0.f);
  }
  float r2[16];
  #pragma unroll
  for (int j = 0; j < 16; ++j){
    float s = s_b2[j];
    #pragma unroll 8
    for (int c = 0; c < 32; ++c) s = fmaf(r1[c], s_w2[c*16 + j], s);
    r2[j] = fmaxf(s, 0.f);
  }
  float s = b3[0];
  #pragma unroll
  for (int c = 0; c < 16; ++c) s = fmaf(r2[c], s_w3[c], s);
  out[g] = s;
}

// ---------------------------------------------------------------------------
template<int BN, int BK>
static inline void launch_hgemm(hipStream_t st,
    const f16* A1, int lda1, int K1, const f16* A2, int lda2, int K2,
    const f16* Bpk, int Kp, const float* bias,
    f16* C, int ldc, int M, int Ncols, int mode,
    const f16* ep, int ldep,
    const float* g, const float* b, const float* m, const float* v,
    int headOff = 0, size_t pstride = 0, int hcShift = 0)
{
  dim3 grid(Ncols / BN, (M + 127) / 128, 1);
  hgemm_kernel<BN,BK><<<grid, 256, 0, st>>>(A1, lda1, K1, A2, lda2, K2, Bpk, Kp,
                                            bias, C, ldc, M, mode, ep, ldep, g, b, m, v,
                                            headOff, pstride, hcShift);
}

struct ConvW {
  const float *wq,*bq,*wk,*bk,*wv,*bv,*we,*ws,*bs,*bg,*bb,*bm,*bv_;
};

extern "C" void kernel_launch(void* const* d_in, const int* in_sizes, int n_in,
                              void* d_out, int out_size, void* d_ws, size_t ws_size,
                              hipStream_t stream) {
  (void)n_in;
  const float* x     = (const float*)d_in[0];
  const int*   ei    = (const int*)d_in[1];
  const float* eattr = (const float*)d_in[2];
  const int*   batch = (const int*)d_in[3];
  const float* ee_w1 = (const float*)d_in[4];
  const float* ee_b1 = (const float*)d_in[5];
  const float* ee_w2 = (const float*)d_in[6];
  const float* ee_b2 = (const float*)d_in[7];
  ConvW cw[3];
  {
    int t = 8;
    for (int c = 0; c < 3; ++c){
      cw[c].wq=(const float*)d_in[t++]; cw[c].bq=(const float*)d_in[t++];
      cw[c].wk=(const float*)d_in[t++]; cw[c].bk=(const float*)d_in[t++];
      cw[c].wv=(const float*)d_in[t++]; cw[c].bv=(const float*)d_in[t++];
      cw[c].we=(const float*)d_in[t++]; cw[c].ws=(const float*)d_in[t++]; cw[c].bs=(const float*)d_in[t++];
    }
    for (int c = 0; c < 3; ++c){
      cw[c].bg=(const float*)d_in[t++]; cw[c].bb=(const float*)d_in[t++];
      cw[c].bm=(const float*)d_in[t++]; cw[c].bv_=(const float*)d_in[t++];
    }
  }
  const float* r_w1 = (const float*)d_in[47];
  const float* r_b1 = (const float*)d_in[48];
  const float* r_w2 = (const float*)d_in[49];
  const float* r_b2 = (const float*)d_in[50];
  const float* r_w3 = (const float*)d_in[51];
  const float* r_b3 = (const float*)d_in[52];

  const int N = in_sizes[0] / 64;      // 50000
  const int E = in_sizes[2] / 16;      // 400000
  const int G = out_size;              // 128

  // ---- workspace layout (A-source buffers padded 128 rows for gload) ----
  const size_t NPAD = (size_t)N + 128;
  char* wp = (char*)d_ws;
  f16* HA   = (f16*)wp;            wp += NPAD*256*2;
  f16* HB   = (f16*)wp;            wp += NPAD*256*2;
  f16* PROJ = (f16*)wp;            wp += NPAD*1024*2;
  f16* EFh  = (f16*)wp;            wp += (size_t)E*64*2;
  f16* Bpk  = (f16*)wp;            wp += 534528*2;
  float* biasAll = (float*)wp;     wp += 2304*4;
  float* gsum    = (float*)wp;     wp += 8192*4;
  int* ideg  = (int*)wp;           wp += (size_t)N*4;
  int* icnt  = (int*)wp;           wp += (size_t)N*4;
  int* irow  = (int*)wp;           wp += (size_t)(N+1)*4;
  int* csr_s = (int*)wp;           wp += (size_t)E*4;
  int* csr_e = (int*)wp;           wp += (size_t)E*4;
  size_t used = (size_t)(wp - (char*)d_ws);
  if (used > ws_size) {
    leak_kernel<<<(G + 255)/256, 256, 0, stream>>>((float*)d_out, G, (float)(ws_size >> 20));
    return;
  }
  // encoder-phase aliases (dead before/overwritten after use):
  f16* EA16  = HB;                  // [E,16] in HB (HB written first by conv1 post)
  f16* HID   = PROJ;                // [E,64]
  f16* EFtmp = PROJ + (size_t)E*64; // [E,64]

  const int* src = ei;
  const int* dst = ei + E;

  // Bpk job offsets
  const int BO_E1 = 0, BO_E2 = 2048, BO_P0 = 6144, BO_P1 = 71680, BO_P2 = 333824;
  const int BO_S0 = 399360, BO_S1 = 432128, BO_S2 = 514048;

  // ---- prep: weights + bias + zero(gsum/ideg/icnt) + cvt16(eattr,x) ----
  PrepP P;
  P.ee_w1 = ee_w1; P.ee_w2 = ee_w2;
  for (int c = 0; c < 3; ++c){
    P.wq[c]=cw[c].wq; P.wk[c]=cw[c].wk; P.wv[c]=cw[c].wv; P.we[c]=cw[c].we; P.ws[c]=cw[c].ws;
    P.bq[c]=cw[c].bq; P.bk[c]=cw[c].bk; P.bv[c]=cw[c].bv;
  }
  P.Bpk = Bpk; P.biasAll = biasAll;
  P.zeroP = (int*)gsum; P.nZero = 8192 + 2*N;
  P.eattr = eattr; P.EA16 = EA16; P.nEA = E*16;
  P.x = x; P.XA = HA; P.nXA = N*64;
  {
    long total = 534528 + 2304 + (long)P.nZero + P.nEA + P.nXA;
    prep_kernel<<<(int)((total + 255)/256), 256, 0, stream>>>(P);
  }

  // ---- CSR by dst ----
  hist_kernel<<<(E + 255)/256, 256, 0, stream>>>(dst, ideg, E);
  scan_kernel<<<1, 1024, 0, stream>>>(ideg, irow, N);
  scatter_kernel<<<(E + 255)/256, 256, 0, stream>>>(src, dst, irow, icnt, csr_s, csr_e, E);

  // ---- edge encoder: e = relu(ea@W1+b1)@W2+b2 ----
  launch_hgemm<64,32>(stream, EA16, 16, 32, nullptr, 0, 0, Bpk + BO_E1, 32, ee_b1,
                      HID, 64, E, 64, 1, nullptr, 0, 0,0,0,0);
  launch_hgemm<64,64>(stream, HID, 64, 64, nullptr, 0, 0, Bpk + BO_E2, 64, ee_b2,
                      EFtmp, 64, E, 64, 0, nullptr, 0, 0,0,0,0);
  gather_ef16_kernel<<<(E*8 + 255)/256, 256, 0, stream>>>(EFtmp, csr_e, EFh, E);

  // ================= conv layers =================
  const int BO_P[3] = {BO_P0, BO_P1, BO_P2};
  const int BO_S[3] = {BO_S0, BO_S1, BO_S2};
  const int bOff[3] = {0, 1024, 2048};
  for (int c = 0; c < 3; ++c) {
    const int din = (c == 0) ? 64 : 256;
    const int H   = (c == 2) ? 1 : 4;
    const int hc  = H * 64;
    const int hcShift = (hc == 256) ? 8 : 6;
    const size_t ps = NPAD * (size_t)hc;
    const f16* Xin = (c == 0) ? HA : ((c == 1) ? HB : HA);
    const int  ldx = (c == 0) ? 64 : 256;
    f16* Hout = (c == 1) ? HA : HB;
    const ConvW& W = cw[c];

    // fused projection into planes: [Q|K|V|QWE] each [N,hc]
    launch_hgemm<128,64>(stream, Xin, ldx, din, nullptr, 0, 0, Bpk + BO_P[c], din,
                         biasAll + bOff[c], PROJ, hc, N, 4*hc, 0, nullptr, 0, 0,0,0,0,
                         0, ps, hcShift);

    // aggregation (att -> Q plane, SE -> QWE plane)
    if (H == 4) agg16_kernel<256><<<(N + 3)/4,  256, 0, stream>>>(irow, csr_s, PROJ, ps, EFh, N);
    else        agg16_kernel<64> <<<(N + 15)/16,256, 0, stream>>>(irow, csr_s, PROJ, ps, EFh, N);

    // post: Hout = BN_ELU( SE_h@we_h + X@ws + bs + att ), Kpp = 64+din
    launch_hgemm<64,64>(stream, PROJ + 3*ps, hc, 64, Xin, ldx, din, Bpk + BO_S[c], 64 + din,
                        W.bs, Hout, hc, N, hc, 2, PROJ, hc, W.bg, W.bb, W.bm, W.bv_,
                        1, 0, 0);
  }

  // ---- global mean pool + MLP ----
  {
    int chunks = (N + 63) / 64;
    pool16_kernel<<<(chunks + 3)/4, 256, 0, stream>>>(HB, batch, gsum, N);
  }
  mlp_kernel<<<1, 128, 0, stream>>>(gsum, batch, N, G, r_w1, r_b1, r_w2, r_b2, r_w3, r_b3,
                                    (float*)d_out);
}

// Round 10
// 792.654 us; speedup vs baseline: 1.0471x; 1.0471x over previous
//
#include <hip/hip_runtime.h>
#include <math.h>

// ---------------------------------------------------------------------------
// GTR_50139448214076: 3x TransformerConv GNN + BN/ELU + mean-pool + MLP
// All GEMMs MFMA fp16, activations fp16, fp32 acc.
// R10: BK=32 everywhere (R8's proven 16KB-LDS config; BK=64 killed occupancy)
//      + LDS-staged MLP head (R9's win, 110us -> ~6us).
// ---------------------------------------------------------------------------

typedef _Float16 f16;
typedef _Float16 half8  __attribute__((ext_vector_type(8)));
typedef _Float16 half4v __attribute__((ext_vector_type(4)));
typedef float    f32x4  __attribute__((ext_vector_type(4)));

__device__ __forceinline__ void gload16(const void* g, void* l){
  __builtin_amdgcn_global_load_lds((const __attribute__((address_space(1))) void*)g,
                                   (__attribute__((address_space(3))) void*)l, 16, 0, 0);
}

// ---------------- utility ----------------
__global__ void leak_kernel(float* __restrict__ out, int n, float val){
  int i = blockIdx.x*blockDim.x + threadIdx.x;
  if (i < n) out[i] = val;
}

// ---------------- CSR build ----------------
__global__ void hist_kernel(const int* __restrict__ dst, int* __restrict__ deg, int E){
  int i = blockIdx.x*blockDim.x + threadIdx.x;
  if (i < E) atomicAdd(&deg[dst[i]], 1);
}

__global__ __launch_bounds__(1024)
void scan_kernel(const int* __restrict__ deg, int* __restrict__ rowptr, int n){
  __shared__ int buf[1024];
  __shared__ int sbase;
  int tid = threadIdx.x;
  if (tid == 0){ sbase = 0; rowptr[0] = 0; }
  __syncthreads();
  for (int start = 0; start < n; start += 4096){
    int i0 = start + tid*4;
    int a0 = (i0+0<n)?deg[i0+0]:0;
    int a1 = (i0+1<n)?deg[i0+1]:0;
    int a2 = (i0+2<n)?deg[i0+2]:0;
    int a3 = (i0+3<n)?deg[i0+3]:0;
    int s = a0+a1+a2+a3;
    int v = s;
    buf[tid] = v;
    __syncthreads();
    for (int off=1; off<1024; off<<=1){
      int t = (tid >= off) ? buf[tid-off] : 0;
      __syncthreads();
      v += t;
      buf[tid] = v;
      __syncthreads();
    }
    int pre = sbase + v - s;
    if (i0+0 < n) rowptr[i0+1] = pre + a0;
    if (i0+1 < n) rowptr[i0+2] = pre + a0 + a1;
    if (i0+2 < n) rowptr[i0+3] = pre + a0 + a1 + a2;
    if (i0+3 < n) rowptr[i0+4] = pre + s;
    __syncthreads();
    if (tid == 1023) sbase += buf[1023];
    __syncthreads();
  }
}

__global__ void scatter_kernel(const int* __restrict__ src, const int* __restrict__ dst,
                               const int* __restrict__ rowptr, int* __restrict__ cnt,
                               int* __restrict__ csr_src, int* __restrict__ csr_eid, int E){
  int i = blockIdx.x*blockDim.x + threadIdx.x;
  if (i >= E) return;
  int d = dst[i];
  int pos = rowptr[d] + atomicAdd(&cnt[d], 1);
  csr_src[pos] = src[i];
  csr_eid[pos] = i;
}

// EFh[i] = EFt[csr_eid[i]]  (fp16 edge features -> CSR order)
__global__ void gather_ef16_kernel(const f16* __restrict__ EFt, const int* __restrict__ csr_eid,
                                   f16* __restrict__ EFh, int E){
  int i = blockIdx.x*blockDim.x + threadIdx.x;   // E*8 chunks of 8 halves
  if (i >= E*8) return;
  int e = i >> 3, j8 = (i & 7) * 8;
  *(half8*)(EFh + (size_t)e*64 + j8) = *(const half8*)(EFt + (size_t)csr_eid[e]*64 + j8);
}

// ---------------- unified prep: weight pack + bias + zero + cvt ----------------
// Bpk layout (halves), B^T [col][Kp]:
//  [0,2048)        enc1: 64 x 32  (ee_w1, K=16 zero-padded)
//  [2048,6144)     enc2: 64 x 64
//  [6144,71680)    proj0: 1024 x 64   [wq|wk|wv|wqe]
//  [71680,333824)  proj1: 1024 x 256
//  [333824,399360) proj2: 256 x 256
//  [399360,432128) post0: 256 x 128   [we(compact);ws], Kpp=64+din
//  [432128,514048) post1: 256 x 320
//  [514048,534528) post2: 64 x 320
// biasAll (fp32): [0,1024) conv0 [bq|bk|bv|bqe]; [1024,2048) conv1; [2048,2304) conv2
struct PrepP {
  const float *ee_w1, *ee_w2;
  const float *wq[3], *wk[3], *wv[3], *we[3], *ws[3];
  const float *bq[3], *bk[3], *bv[3];
  f16* Bpk; float* biasAll;
  int* zeroP; int nZero;
  const float* eattr; f16* EA16; int nEA;
  const float* x; f16* XA; int nXA;
};

__device__ __forceinline__ float projv(const float* wq, const float* wk, const float* wv,
                                       const float* we, int hc, int din, int x){
  int c = x / din, k = x - c*din;
  int sec = c / hc, cc = c - sec*hc;
  if (sec == 0) return wq[(size_t)k*hc + cc];
  if (sec == 1) return wk[(size_t)k*hc + cc];
  if (sec == 2) return wv[(size_t)k*hc + cc];
  int h = cc >> 6, jj = cc & 63;
  const float* q = wq + (size_t)k*hc + h*64;
  const float* w = we + (size_t)jj*hc + h*64;
  float s = 0.f;
  #pragma unroll 8
  for (int t = 0; t < 64; ++t) s += q[t]*w[t];
  return s;
}
__device__ __forceinline__ float postv(const float* we, const float* ws,
                                       int hc, int din, int x){
  int Kpp = 64 + din;
  int c = x / Kpp, k = x - c*Kpp;
  if (k < 64) return we[(size_t)k*hc + c];
  return ws[(size_t)(k-64)*hc + c];
}

__global__ void prep_kernel(PrepP P){
  int id = blockIdx.x*blockDim.x + threadIdx.x;
  const int NB = 534528, NBB = NB + 2304;
  if (id < NB){
    float v;
    if      (id < 2048)  { int c = id>>5, k = id&31; v = (k<16) ? P.ee_w1[k*64 + c] : 0.f; }
    else if (id < 6144)  { int x = id-2048; int c = x>>6, k = x&63; v = P.ee_w2[k*64 + c]; }
    else if (id < 71680) v = projv(P.wq[0],P.wk[0],P.wv[0],P.we[0],256,64, id-6144);
    else if (id < 333824)v = projv(P.wq[1],P.wk[1],P.wv[1],P.we[1],256,256,id-71680);
    else if (id < 399360)v = projv(P.wq[2],P.wk[2],P.wv[2],P.we[2],64, 256,id-333824);
    else if (id < 432128)v = postv(P.we[0],P.ws[0],256,64, id-399360);
    else if (id < 514048)v = postv(P.we[1],P.ws[1],256,256,id-432128);
    else                 v = postv(P.we[2],P.ws[2],64, 256,id-514048);
    P.Bpk[id] = (f16)v;
  } else if (id < NBB){
    int x = id - NB;
    int cv, off, hc;
    if (x < 1024){ cv = 0; off = x;        hc = 256; }
    else if (x < 2048){ cv = 1; off = x-1024; hc = 256; }
    else { cv = 2; off = x-2048; hc = 64; }
    int sec = off / hc, cc = off - sec*hc;
    float v;
    if      (sec == 0) v = P.bq[cv][cc];
    else if (sec == 1) v = P.bk[cv][cc];
    else if (sec == 2) v = P.bv[cv][cc];
    else {
      int h = cc >> 6, jj = cc & 63;
      const float* b = P.bq[cv] + h*64;
      const float* w = P.we[cv] + (size_t)jj*hc + h*64;
      v = 0.f;
      #pragma unroll 8
      for (int t = 0; t < 64; ++t) v += b[t]*w[t];
    }
    P.biasAll[x] = v;
  } else if (id < NBB + P.nZero){
    P.zeroP[id - NBB] = 0;
  } else if (id < NBB + P.nZero + P.nEA){
    int i = id - NBB - P.nZero;
    P.EA16[i] = (f16)P.eattr[i];
  } else if (id < NBB + P.nZero + P.nEA + P.nXA){
    int i = id - NBB - P.nZero - P.nEA;
    P.XA[i] = (f16)P.x[i];
  }
}

// ---------------- MFMA fp16 GEMM (gload_lds + XOR swizzle, 128xBN, BK=32) ---
// C = [A1 | A2] @ Bpk + bias.  Grid (Ncols/BN, ceil(M/128)).
// LDS slot (row r, chunk c) holds global chunk c ^ ((r>>2)&3); staged via
// pre-swizzled per-lane global source. A sources padded 128 rows past M.
// headOff: A1 += col0 (post GEMM per-head SE slice).
// pstride!=0: plane-split C write.
// mode 0: +bias; 1: +bias,relu; 2: +bias +ep(f16,ldep) +BN +ELU.
__device__ __forceinline__ float bn_elu(float x, float g, float b, float m, float v){
  float s = g / sqrtf(v + 1e-5f);
  float y = (x - m) * s + b;
  return y > 0.f ? y : expm1f(y);
}

template<int BN>
__global__ __launch_bounds__(256)
void hgemm_kernel(const f16* __restrict__ A1, int lda1, int K1,
                  const f16* __restrict__ A2, int lda2, int K2,
                  const f16* __restrict__ Bpk, int Kp,
                  const float* __restrict__ bias,
                  f16* __restrict__ C, int ldc, int M, int mode,
                  const f16* __restrict__ ep, int ldep,
                  const float* __restrict__ bng, const float* __restrict__ bnb,
                  const float* __restrict__ bnm, const float* __restrict__ bnv,
                  int headOff, size_t pstride, int hcShift)
{
  constexpr int WM = (BN == 128) ? 64 : 32;
  constexpr int MF = WM / 16;
  __shared__ f16 As[128*32];
  __shared__ f16 Bs[BN*32];
  const int tid  = threadIdx.x;
  const int lane = tid & 63;
  const int wave = tid >> 6;
  const int wm   = (BN == 128) ? (wave >> 1) : wave;
  const int wn   = (BN == 128) ? (wave & 1) : 0;
  const int l15  = lane & 15;
  const int cs   = (lane >> 4) ^ ((lane >> 2) & 3);   // fragment-read chunk
  const int csl  = (lane & 3) ^ (lane >> 4);          // staging source chunk
  const int arow = lane >> 2;                         // staging row-in-group

  // XCD-chunked bijective swizzle
  const int nbx = gridDim.x;
  const int nwg = nbx * gridDim.y;
  int bid = blockIdx.y * nbx + blockIdx.x;
  {
    int q = nwg >> 3, r = nwg & 7;
    int xcd = bid & 7, idx = bid >> 3;
    bid = (xcd < r ? xcd * (q + 1) : r * (q + 1) + (xcd - r) * q) + idx;
  }
  const int row0 = (bid / nbx) * 128;
  const int col0 = (bid % nbx) * BN;
  const f16* A1b = headOff ? (A1 + col0) : A1;

  f32x4 acc[MF*4];
  #pragma unroll
  for (int i = 0; i < MF*4; ++i){ acc[i][0]=0.f; acc[i][1]=0.f; acc[i][2]=0.f; acc[i][3]=0.f; }

  for (int k0 = 0; k0 < Kp; k0 += 32) {
    const f16* Ap; int lda, ks;
    if (k0 < K1) { Ap = A1b; lda = lda1; ks = k0; }
    else         { Ap = A2;  lda = lda2; ks = k0 - K1; }
    // stage A: wave covers rows [wave*32, wave*32+32), 2 issues of 16 rows
    #pragma unroll
    for (int t = 0; t < 2; ++t) {
      int r = wave*32 + t*16 + arow;
      gload16(Ap + (size_t)(row0 + r)*lda + ks + csl*8, As + (wave*32 + t*16)*32);
    }
    // stage B
    if (BN == 128) {
      #pragma unroll
      for (int t = 0; t < 2; ++t) {
        int r = wave*32 + t*16 + arow;
        gload16(Bpk + (size_t)(col0 + r)*Kp + k0 + csl*8, Bs + (wave*32 + t*16)*32);
      }
    } else {
      int r = wave*16 + arow;
      gload16(Bpk + (size_t)(col0 + r)*Kp + k0 + csl*8, Bs + wave*16*32);
    }
    __syncthreads();   // drains vmcnt (compiler emits s_waitcnt vmcnt(0))

    half8 af[MF], bf[4];
    #pragma unroll
    for (int mf = 0; mf < MF; ++mf)
      af[mf] = *(const half8*)(As + (wm*WM + mf*16 + l15)*32 + cs*8);
    #pragma unroll
    for (int nf = 0; nf < 4; ++nf)
      bf[nf] = *(const half8*)(Bs + (wn*64 + nf*16 + l15)*32 + cs*8);
    #pragma unroll
    for (int mf = 0; mf < MF; ++mf)
      #pragma unroll
      for (int nf = 0; nf < 4; ++nf)
        acc[mf*4+nf] = __builtin_amdgcn_mfma_f32_16x16x32_f16(af[mf], bf[nf], acc[mf*4+nf], 0,0,0);
    __syncthreads();
  }

  // epilogue: C/D layout col=lane&15, row=(lane>>4)*4+reg
  #pragma unroll
  for (int mf = 0; mf < MF; ++mf)
    #pragma unroll
    for (int nf = 0; nf < 4; ++nf){
      int col  = col0 + wn*64 + nf*16 + l15;
      int rowb = row0 + wm*WM + mf*16 + (lane>>4)*4;
      float bi = bias ? bias[col] : 0.f;
      #pragma unroll
      for (int i = 0; i < 4; ++i){
        int row = rowb + i;
        if (row >= M) continue;
        float r = acc[mf*4+nf][i] + bi;
        if (mode == 1) r = fmaxf(r, 0.f);
        else if (mode == 2){
          r += (float)ep[(size_t)row*ldep + col];
          r = bn_elu(r, bng[col], bnb[col], bnm[col], bnv[col]);
        }
        if (pstride){
          int hc = 1 << hcShift;
          int plane = col >> hcShift, c2 = col & (hc - 1);
          C[(size_t)plane*pstride + (size_t)row*hc + c2] = (f16)r;
        } else {
          C[(size_t)row*ldc + col] = (f16)r;
        }
      }
    }
}

// ---------------- aggregation: online softmax, 2-deep pipelined -------------
// Planes: Q=PROJ, K=PROJ+ps, V=+2ps, QWE=+3ps; each [N,HC] compact.
// att overwrites Q plane row, SE overwrites QWE plane row.
template<int HC>
__global__ __launch_bounds__(256)
void agg16_kernel(const int* __restrict__ rowptr, const int* __restrict__ csr_src,
                  f16* __restrict__ PROJ, size_t ps, const f16* __restrict__ EFh, int nNodes)
{
  int lane = threadIdx.x & 63;
  int wid = (blockIdx.x * blockDim.x + threadIdx.x) >> 6;
  int grp = lane >> 4, l16 = lane & 15;
  int node, ch;
  if (HC == 256) { node = wid;          ch = 4*lane; }
  else           { node = wid*4 + grp;  ch = 4*l16;  }
  if (node >= nNodes) return;
  f16* Qp = PROJ;
  const f16* Kp = PROJ + ps;
  const f16* Vp = PROJ + 2*ps;
  f16* Wp = PROJ + 3*ps;
  half4v qh = *(const half4v*)(Qp + (size_t)node*HC + ch);
  half4v wh = *(const half4v*)(Wp + (size_t)node*HC + ch);
  float q0=qh[0],q1=qh[1],q2=qh[2],q3=qh[3];
  float w0=wh[0],w1=wh[1],w2=wh[2],w3=wh[3];
  int e0 = rowptr[node], e1 = rowptr[node+1];

  float m = -INFINITY, den = 0.f;
  float avx=0.f,avy=0.f,avz=0.f,avw=0.f, aex=0.f,aey=0.f,aez=0.f,aew=0.f;

  half4v kN, vN, eN;
  if (e0 < e1) {
    size_t so = (size_t)csr_src[e0]*HC + ch;
    kN = *(const half4v*)(Kp + so);
    vN = *(const half4v*)(Vp + so);
    eN = *(const half4v*)(EFh + (size_t)e0*64 + 4*l16);
  }
  for (int i = e0; i < e1; ++i) {
    half4v k4 = kN, v4 = vN, e4 = eN;
    if (i + 1 < e1) {
      size_t so = (size_t)csr_src[i+1]*HC + ch;
      kN = *(const half4v*)(Kp + so);
      vN = *(const half4v*)(Vp + so);
      eN = *(const half4v*)(EFh + (size_t)(i+1)*64 + 4*l16);
    }
    float ex=e4[0], ey=e4[1], ez=e4[2], ew=e4[3];
    float p = q0*(float)k4[0] + q1*(float)k4[1] + q2*(float)k4[2] + q3*(float)k4[3]
            + w0*ex + w1*ey + w2*ez + w3*ew;
    p += __shfl_xor(p, 1);
    p += __shfl_xor(p, 2);
    p += __shfl_xor(p, 4);
    p += __shfl_xor(p, 8);
    float alpha = p * 0.125f;       // 1/sqrt(64)
    float mn = fmaxf(m, alpha);
    float sc = __expf(m - mn);      // -inf -> 0 on first edge
    float w  = __expf(alpha - mn);
    den = den*sc + w;
    avx = avx*sc + w*(float)v4[0]; avy = avy*sc + w*(float)v4[1];
    avz = avz*sc + w*(float)v4[2]; avw = avw*sc + w*(float)v4[3];
    aex = aex*sc + w*ex; aey = aey*sc + w*ey;
    aez = aez*sc + w*ez; aew = aew*sc + w*ew;
    m = mn;
  }
  float inv = den > 0.f ? 1.0f/den : 0.f;
  half4v o1, o2;
  o1[0]=(f16)(avx*inv); o1[1]=(f16)(avy*inv); o1[2]=(f16)(avz*inv); o1[3]=(f16)(avw*inv);
  o2[0]=(f16)(aex*inv); o2[1]=(f16)(aey*inv); o2[2]=(f16)(aez*inv); o2[3]=(f16)(aew*inv);
  *(half4v*)(Qp + (size_t)node*HC + ch) = o1;
  *(half4v*)(Wp + (size_t)node*HC + ch) = o2;
}

// ---------------- mean pool (batch sorted, fp16 in) ----------------
__global__ void pool16_kernel(const f16* __restrict__ Hf, const int* __restrict__ batch,
                              float* __restrict__ gsum, int nNodes){
  const int CH = 64;
  int c = threadIdx.x & 63;
  int chunk = blockIdx.x * (blockDim.x >> 6) + (threadIdx.x >> 6);
  int n0 = chunk * CH;
  if (n0 >= nNodes) return;
  int n1 = min(n0 + CH, nNodes);
  float acc = 0.f;
  int g = batch[n0];
  for (int n = n0; n < n1; ++n) {
    int gn = batch[n];
    if (gn != g) { atomicAdd(&gsum[g*64 + c], acc); acc = 0.f; g = gn; }
    acc += (float)Hf[(size_t)n*64 + c];
  }
  atomicAdd(&gsum[g*64 + c], acc);
}

// ---------------- MLP head: weights staged in LDS (fp32) ----------------
__global__ void mlp_kernel(const float* __restrict__ gsum, const int* __restrict__ batch,
                           int nNodes, int G,
                           const float* __restrict__ w1, const float* __restrict__ b1,
                           const float* __restrict__ w2, const float* __restrict__ b2,
                           const float* __restrict__ w3, const float* __restrict__ b3,
                           float* __restrict__ out){
  __shared__ float s_w1[2048], s_w2[512], s_w3[16], s_b1[32], s_b2[16];
  int t = threadIdx.x;
  for (int i = t; i < 2048; i += 128) s_w1[i] = w1[i];
  for (int i = t; i < 512;  i += 128) s_w2[i] = w2[i];
  if (t < 16) s_w3[t] = w3[t];
  if (t < 32) s_b1[t] = b1[t];
  if (t < 16) s_b2[t] = b2[t];
  __syncthreads();
  int g = t;
  if (g >= G) return;
  int lo = 0, hi = nNodes;
  while (lo < hi){ int mid = (lo+hi)>>1; if (batch[mid] < g) lo = mid+1; else hi = mid; }
  int first = lo;
  lo = 0; hi = nNodes;
  while (lo < hi){ int mid = (lo+hi)>>1; if (batch[mid] < g+1) lo = mid+1; else hi = mid; }
  int cnt = lo - first;
  float invc = 1.0f / fmaxf((float)cnt, 1.0f);
  float gm[64];
  #pragma unroll
  for (int c = 0; c < 64; ++c) gm[c] = gsum[g*64 + c] * invc;
  float r1[32];
  #pragma unroll
  for (int j = 0; j < 32; ++j){
    float s = s_b1[j];
    #pragma unroll 8
    for (int c = 0; c < 64; ++c) s = fmaf(gm[c], s_w1[c*32 + j], s);
    r1[j] = fmaxf(s, 0.f);
  }
  float r2[16];
  #pragma unroll
  for (int j = 0; j < 16; ++j){
    float s = s_b2[j];
    #pragma unroll 8
    for (int c = 0; c < 32; ++c) s = fmaf(r1[c], s_w2[c*16 + j], s);
    r2[j] = fmaxf(s, 0.f);
  }
  float s = b3[0];
  #pragma unroll
  for (int c = 0; c < 16; ++c) s = fmaf(r2[c], s_w3[c], s);
  out[g] = s;
}

// ---------------------------------------------------------------------------
template<int BN>
static inline void launch_hgemm(hipStream_t st,
    const f16* A1, int lda1, int K1, const f16* A2, int lda2, int K2,
    const f16* Bpk, int Kp, const float* bias,
    f16* C, int ldc, int M, int Ncols, int mode,
    const f16* ep, int ldep,
    const float* g, const float* b, const float* m, const float* v,
    int headOff = 0, size_t pstride = 0, int hcShift = 0)
{
  dim3 grid(Ncols / BN, (M + 127) / 128, 1);
  hgemm_kernel<BN><<<grid, 256, 0, st>>>(A1, lda1, K1, A2, lda2, K2, Bpk, Kp,
                                         bias, C, ldc, M, mode, ep, ldep, g, b, m, v,
                                         headOff, pstride, hcShift);
}

struct ConvW {
  const float *wq,*bq,*wk,*bk,*wv,*bv,*we,*ws,*bs,*bg,*bb,*bm,*bv_;
};

extern "C" void kernel_launch(void* const* d_in, const int* in_sizes, int n_in,
                              void* d_out, int out_size, void* d_ws, size_t ws_size,
                              hipStream_t stream) {
  (void)n_in;
  const float* x     = (const float*)d_in[0];
  const int*   ei    = (const int*)d_in[1];
  const float* eattr = (const float*)d_in[2];
  const int*   batch = (const int*)d_in[3];
  const float* ee_w1 = (const float*)d_in[4];
  const float* ee_b1 = (const float*)d_in[5];
  const float* ee_w2 = (const float*)d_in[6];
  const float* ee_b2 = (const float*)d_in[7];
  ConvW cw[3];
  {
    int t = 8;
    for (int c = 0; c < 3; ++c){
      cw[c].wq=(const float*)d_in[t++]; cw[c].bq=(const float*)d_in[t++];
      cw[c].wk=(const float*)d_in[t++]; cw[c].bk=(const float*)d_in[t++];
      cw[c].wv=(const float*)d_in[t++]; cw[c].bv=(const float*)d_in[t++];
      cw[c].we=(const float*)d_in[t++]; cw[c].ws=(const float*)d_in[t++]; cw[c].bs=(const float*)d_in[t++];
    }
    for (int c = 0; c < 3; ++c){
      cw[c].bg=(const float*)d_in[t++]; cw[c].bb=(const float*)d_in[t++];
      cw[c].bm=(const float*)d_in[t++]; cw[c].bv_=(const float*)d_in[t++];
    }
  }
  const float* r_w1 = (const float*)d_in[47];
  const float* r_b1 = (const float*)d_in[48];
  const float* r_w2 = (const float*)d_in[49];
  const float* r_b2 = (const float*)d_in[50];
  const float* r_w3 = (const float*)d_in[51];
  const float* r_b3 = (const float*)d_in[52];

  const int N = in_sizes[0] / 64;      // 50000
  const int E = in_sizes[2] / 16;      // 400000
  const int G = out_size;              // 128

  // ---- workspace layout (A-source buffers padded 128 rows for gload) ----
  const size_t NPAD = (size_t)N + 128;
  char* wp = (char*)d_ws;
  f16* HA   = (f16*)wp;            wp += NPAD*256*2;
  f16* HB   = (f16*)wp;            wp += NPAD*256*2;
  f16* PROJ = (f16*)wp;            wp += NPAD*1024*2;
  f16* EFh  = (f16*)wp;            wp += (size_t)E*64*2;
  f16* Bpk  = (f16*)wp;            wp += 534528*2;
  float* biasAll = (float*)wp;     wp += 2304*4;
  float* gsum    = (float*)wp;     wp += 8192*4;
  int* ideg  = (int*)wp;           wp += (size_t)N*4;
  int* icnt  = (int*)wp;           wp += (size_t)N*4;
  int* irow  = (int*)wp;           wp += (size_t)(N+1)*4;
  int* csr_s = (int*)wp;           wp += (size_t)E*4;
  int* csr_e = (int*)wp;           wp += (size_t)E*4;
  size_t used = (size_t)(wp - (char*)d_ws);
  if (used > ws_size) {
    leak_kernel<<<(G + 255)/256, 256, 0, stream>>>((float*)d_out, G, (float)(ws_size >> 20));
    return;
  }
  // encoder-phase aliases (dead before/overwritten after use):
  f16* EA16  = HB;                  // [E,16] in HB (HB written first by conv1 post)
  f16* HID   = PROJ;                // [E,64]
  f16* EFtmp = PROJ + (size_t)E*64; // [E,64]

  const int* src = ei;
  const int* dst = ei + E;

  // Bpk job offsets
  const int BO_E1 = 0, BO_E2 = 2048, BO_P0 = 6144, BO_P1 = 71680, BO_P2 = 333824;
  const int BO_S0 = 399360, BO_S1 = 432128, BO_S2 = 514048;

  // ---- prep: weights + bias + zero(gsum/ideg/icnt) + cvt16(eattr,x) ----
  PrepP P;
  P.ee_w1 = ee_w1; P.ee_w2 = ee_w2;
  for (int c = 0; c < 3; ++c){
    P.wq[c]=cw[c].wq; P.wk[c]=cw[c].wk; P.wv[c]=cw[c].wv; P.we[c]=cw[c].we; P.ws[c]=cw[c].ws;
    P.bq[c]=cw[c].bq; P.bk[c]=cw[c].bk; P.bv[c]=cw[c].bv;
  }
  P.Bpk = Bpk; P.biasAll = biasAll;
  P.zeroP = (int*)gsum; P.nZero = 8192 + 2*N;
  P.eattr = eattr; P.EA16 = EA16; P.nEA = E*16;
  P.x = x; P.XA = HA; P.nXA = N*64;
  {
    long total = 534528 + 2304 + (long)P.nZero + P.nEA + P.nXA;
    prep_kernel<<<(int)((total + 255)/256), 256, 0, stream>>>(P);
  }

  // ---- CSR by dst ----
  hist_kernel<<<(E + 255)/256, 256, 0, stream>>>(dst, ideg, E);
  scan_kernel<<<1, 1024, 0, stream>>>(ideg, irow, N);
  scatter_kernel<<<(E + 255)/256, 256, 0, stream>>>(src, dst, irow, icnt, csr_s, csr_e, E);

  // ---- edge encoder: e = relu(ea@W1+b1)@W2+b2 ----
  launch_hgemm<64>(stream, EA16, 16, 32, nullptr, 0, 0, Bpk + BO_E1, 32, ee_b1,
                   HID, 64, E, 64, 1, nullptr, 0, 0,0,0,0);
  launch_hgemm<64>(stream, HID, 64, 64, nullptr, 0, 0, Bpk + BO_E2, 64, ee_b2,
                   EFtmp, 64, E, 64, 0, nullptr, 0, 0,0,0,0);
  gather_ef16_kernel<<<(E*8 + 255)/256, 256, 0, stream>>>(EFtmp, csr_e, EFh, E);

  // ================= conv layers =================
  const int BO_P[3] = {BO_P0, BO_P1, BO_P2};
  const int BO_S[3] = {BO_S0, BO_S1, BO_S2};
  const int bOff[3] = {0, 1024, 2048};
  for (int c = 0; c < 3; ++c) {
    const int din = (c == 0) ? 64 : 256;
    const int H   = (c == 2) ? 1 : 4;
    const int hc  = H * 64;
    const int hcShift = (hc == 256) ? 8 : 6;
    const size_t ps = NPAD * (size_t)hc;
    const f16* Xin = (c == 0) ? HA : ((c == 1) ? HB : HA);
    const int  ldx = (c == 0) ? 64 : 256;
    f16* Hout = (c == 1) ? HA : HB;
    const ConvW& W = cw[c];

    // fused projection into planes: [Q|K|V|QWE] each [N,hc]
    launch_hgemm<128>(stream, Xin, ldx, din, nullptr, 0, 0, Bpk + BO_P[c], din,
                      biasAll + bOff[c], PROJ, hc, N, 4*hc, 0, nullptr, 0, 0,0,0,0,
                      0, ps, hcShift);

    // aggregation (att -> Q plane, SE -> QWE plane)
    if (H == 4) agg16_kernel<256><<<(N + 3)/4,  256, 0, stream>>>(irow, csr_s, PROJ, ps, EFh, N);
    else        agg16_kernel<64> <<<(N + 15)/16,256, 0, stream>>>(irow, csr_s, PROJ, ps, EFh, N);

    // post: Hout = BN_ELU( SE_h@we_h + X@ws + bs + att ), Kpp = 64+din
    launch_hgemm<64>(stream, PROJ + 3*ps, hc, 64, Xin, ldx, din, Bpk + BO_S[c], 64 + din,
                     W.bs, Hout, hc, N, hc, 2, PROJ, hc, W.bg, W.bb, W.bm, W.bv_,
                     1, 0, 0);
  }

  // ---- global mean pool + MLP ----
  {
    int chunks = (N + 63) / 64;
    pool16_kernel<<<(chunks + 3)/4, 256, 0, stream>>>(HB, batch, gsum, N);
  }
  mlp_kernel<<<1, 128, 0, stream>>>(gsum, batch, N, G, r_w1, r_b1, r_w2, r_b2, r_w3, r_b3,
                                    (float*)d_out);
}

// Round 11
// 655.930 us; speedup vs baseline: 1.2653x; 1.2084x over previous
//
#include <hip/hip_runtime.h>
#include <math.h>

// ---------------------------------------------------------------------------
// GTR_50139448214076: 3x TransformerConv GNN + BN/ELU + mean-pool + MLP
// All GEMMs MFMA fp16 (swapped operands -> packed 8B C-stores), fp32 acc.
// R11: swapped-operand epilogue everywhere; fused encoder kernel
//      (enc1+relu+enc2+CSR-scatter in one, via inv[] permutation).
// ---------------------------------------------------------------------------

typedef _Float16 f16;
typedef _Float16 half8  __attribute__((ext_vector_type(8)));
typedef _Float16 half4v __attribute__((ext_vector_type(4)));
typedef float    f32x4  __attribute__((ext_vector_type(4)));

__device__ __forceinline__ float4 ld4(const float* p){ return *reinterpret_cast<const float4*>(p); }
__device__ __forceinline__ void gload16(const void* g, void* l){
  __builtin_amdgcn_global_load_lds((const __attribute__((address_space(1))) void*)g,
                                   (__attribute__((address_space(3))) void*)l, 16, 0, 0);
}

// ---------------- utility ----------------
__global__ void leak_kernel(float* __restrict__ out, int n, float val){
  int i = blockIdx.x*blockDim.x + threadIdx.x;
  if (i < n) out[i] = val;
}

// ---------------- CSR build ----------------
__global__ void hist_kernel(const int* __restrict__ dst, int* __restrict__ deg, int E){
  int i = blockIdx.x*blockDim.x + threadIdx.x;
  if (i < E) atomicAdd(&deg[dst[i]], 1);
}

__global__ __launch_bounds__(1024)
void scan_kernel(const int* __restrict__ deg, int* __restrict__ rowptr, int n){
  __shared__ int buf[1024];
  __shared__ int sbase;
  int tid = threadIdx.x;
  if (tid == 0){ sbase = 0; rowptr[0] = 0; }
  __syncthreads();
  for (int start = 0; start < n; start += 4096){
    int i0 = start + tid*4;
    int a0 = (i0+0<n)?deg[i0+0]:0;
    int a1 = (i0+1<n)?deg[i0+1]:0;
    int a2 = (i0+2<n)?deg[i0+2]:0;
    int a3 = (i0+3<n)?deg[i0+3]:0;
    int s = a0+a1+a2+a3;
    int v = s;
    buf[tid] = v;
    __syncthreads();
    for (int off=1; off<1024; off<<=1){
      int t = (tid >= off) ? buf[tid-off] : 0;
      __syncthreads();
      v += t;
      buf[tid] = v;
      __syncthreads();
    }
    int pre = sbase + v - s;
    if (i0+0 < n) rowptr[i0+1] = pre + a0;
    if (i0+1 < n) rowptr[i0+2] = pre + a0 + a1;
    if (i0+2 < n) rowptr[i0+3] = pre + a0 + a1 + a2;
    if (i0+3 < n) rowptr[i0+4] = pre + s;
    __syncthreads();
    if (tid == 1023) sbase += buf[1023];
    __syncthreads();
  }
}

// also fills inv[eid] = CSR position (for direct scatter of edge features)
__global__ void scatter_kernel(const int* __restrict__ src, const int* __restrict__ dst,
                               const int* __restrict__ rowptr, int* __restrict__ cnt,
                               int* __restrict__ csr_src, int* __restrict__ inv, int E){
  int i = blockIdx.x*blockDim.x + threadIdx.x;
  if (i >= E) return;
  int d = dst[i];
  int pos = rowptr[d] + atomicAdd(&cnt[d], 1);
  csr_src[pos] = src[i];
  inv[i] = pos;
}

// ---------------- unified prep: weight pack + bias + zero + cvt ----------------
// Bpk layout (halves), B^T [col][Kp]:
//  [0,2048)        enc1: 64 x 32  (ee_w1, K=16 zero-padded)
//  [2048,6144)     enc2: 64 x 64
//  [6144,71680)    proj0: 1024 x 64   [wq|wk|wv|wqe]
//  [71680,333824)  proj1: 1024 x 256
//  [333824,399360) proj2: 256 x 256
//  [399360,432128) post0: 256 x 128   [we(compact);ws], Kpp=64+din
//  [432128,514048) post1: 256 x 320
//  [514048,534528) post2: 64 x 320
// biasAll (fp32): [0,1024) conv0 [bq|bk|bv|bqe]; [1024,2048) conv1; [2048,2304) conv2
struct PrepP {
  const float *ee_w1, *ee_w2;
  const float *wq[3], *wk[3], *wv[3], *we[3], *ws[3];
  const float *bq[3], *bk[3], *bv[3];
  f16* Bpk; float* biasAll;
  int* zeroP; int nZero;
  const float* x; f16* XA; int nXA;
};

__device__ __forceinline__ float projv(const float* wq, const float* wk, const float* wv,
                                       const float* we, int hc, int din, int x){
  int c = x / din, k = x - c*din;
  int sec = c / hc, cc = c - sec*hc;
  if (sec == 0) return wq[(size_t)k*hc + cc];
  if (sec == 1) return wk[(size_t)k*hc + cc];
  if (sec == 2) return wv[(size_t)k*hc + cc];
  int h = cc >> 6, jj = cc & 63;
  const float* q = wq + (size_t)k*hc + h*64;
  const float* w = we + (size_t)jj*hc + h*64;
  float s = 0.f;
  #pragma unroll 8
  for (int t = 0; t < 64; ++t) s += q[t]*w[t];
  return s;
}
__device__ __forceinline__ float postv(const float* we, const float* ws,
                                       int hc, int din, int x){
  int Kpp = 64 + din;
  int c = x / Kpp, k = x - c*Kpp;
  if (k < 64) return we[(size_t)k*hc + c];
  return ws[(size_t)(k-64)*hc + c];
}

__global__ void prep_kernel(PrepP P){
  int id = blockIdx.x*blockDim.x + threadIdx.x;
  const int NB = 534528, NBB = NB + 2304;
  if (id < NB){
    float v;
    if      (id < 2048)  { int c = id>>5, k = id&31; v = (k<16) ? P.ee_w1[k*64 + c] : 0.f; }
    else if (id < 6144)  { int x = id-2048; int c = x>>6, k = x&63; v = P.ee_w2[k*64 + c]; }
    else if (id < 71680) v = projv(P.wq[0],P.wk[0],P.wv[0],P.we[0],256,64, id-6144);
    else if (id < 333824)v = projv(P.wq[1],P.wk[1],P.wv[1],P.we[1],256,256,id-71680);
    else if (id < 399360)v = projv(P.wq[2],P.wk[2],P.wv[2],P.we[2],64, 256,id-333824);
    else if (id < 432128)v = postv(P.we[0],P.ws[0],256,64, id-399360);
    else if (id < 514048)v = postv(P.we[1],P.ws[1],256,256,id-432128);
    else                 v = postv(P.we[2],P.ws[2],64, 256,id-514048);
    P.Bpk[id] = (f16)v;
  } else if (id < NBB){
    int x = id - NB;
    int cv, off, hc;
    if (x < 1024){ cv = 0; off = x;        hc = 256; }
    else if (x < 2048){ cv = 1; off = x-1024; hc = 256; }
    else { cv = 2; off = x-2048; hc = 64; }
    int sec = off / hc, cc = off - sec*hc;
    float v;
    if      (sec == 0) v = P.bq[cv][cc];
    else if (sec == 1) v = P.bk[cv][cc];
    else if (sec == 2) v = P.bv[cv][cc];
    else {
      int h = cc >> 6, jj = cc & 63;
      const float* b = P.bq[cv] + h*64;
      const float* w = P.we[cv] + (size_t)jj*hc + h*64;
      v = 0.f;
      #pragma unroll 8
      for (int t = 0; t < 64; ++t) v += b[t]*w[t];
    }
    P.biasAll[x] = v;
  } else if (id < NBB + P.nZero){
    P.zeroP[id - NBB] = 0;
  } else if (id < NBB + P.nZero + P.nXA){
    int i = id - NBB - P.nZero;
    P.XA[i] = (f16)P.x[i];
  }
}

// ---------------- fused edge encoder ----------------
// EFh[inv[e]] = (relu(eattr[e] @ W1 + b1)) @ W2 + b2   (fp16 out, CSR order)
// Per block: 128 edges. GEMM1 K=16 (A-frags cvt'd from fp32, B from global),
// hid tile in XOR-swizzled LDS, GEMM2 K=64, scatter-write via inv.
// Swapped-operand MFMA: lane holds row l&15, cols (lane>>4)*4 + nf*16 (+i).
__global__ __launch_bounds__(256)
void enc_fused_kernel(const float* __restrict__ eattr,
                      const f16* __restrict__ B1, const f16* __restrict__ B2,
                      const float* __restrict__ b1, const float* __restrict__ b2,
                      const int* __restrict__ inv, f16* __restrict__ EFh, int E)
{
  __shared__ f16 hid[128*64];
  const int tid = threadIdx.x, lane = tid & 63, wave = tid >> 6;
  const int l15 = lane & 15, g = lane >> 4;
  const int row0 = blockIdx.x * 128;   // E % 128 == 0

  // ---- GEMM1 ----
  half8 af[2];
  #pragma unroll
  for (int mf = 0; mf < 2; ++mf){
    int r = row0 + wave*32 + mf*16 + l15;
    half8 v;
    #pragma unroll
    for (int q = 0; q < 8; ++q) v[q] = (f16)0.f;
    if (g < 2){
      const float* p = eattr + (size_t)r*16 + g*8;
      float4 u0 = ld4(p), u1 = ld4(p+4);
      v[0]=(f16)u0.x; v[1]=(f16)u0.y; v[2]=(f16)u0.z; v[3]=(f16)u0.w;
      v[4]=(f16)u1.x; v[5]=(f16)u1.y; v[6]=(f16)u1.z; v[7]=(f16)u1.w;
    }
    af[mf] = v;
  }
  f32x4 acc[8];
  #pragma unroll
  for (int i = 0; i < 8; ++i){ acc[i][0]=0.f; acc[i][1]=0.f; acc[i][2]=0.f; acc[i][3]=0.f; }
  #pragma unroll
  for (int nf = 0; nf < 4; ++nf){
    half8 bf = *(const half8*)(B1 + (size_t)(nf*16 + l15)*32 + g*8);
    #pragma unroll
    for (int mf = 0; mf < 2; ++mf)
      acc[mf*4+nf] = __builtin_amdgcn_mfma_f32_16x16x32_f16(bf, af[mf], acc[mf*4+nf], 0,0,0);
  }
  // relu + b1 -> swizzled LDS hid
  #pragma unroll
  for (int mf = 0; mf < 2; ++mf)
    #pragma unroll
    for (int nf = 0; nf < 4; ++nf){
      int rowL = wave*32 + mf*16 + l15;
      int colb = nf*16 + g*4;
      float4 bi = ld4(&b1[colb]);
      half4v h;
      h[0] = (f16)fmaxf(acc[mf*4+nf][0] + bi.x, 0.f);
      h[1] = (f16)fmaxf(acc[mf*4+nf][1] + bi.y, 0.f);
      h[2] = (f16)fmaxf(acc[mf*4+nf][2] + bi.z, 0.f);
      h[3] = (f16)fmaxf(acc[mf*4+nf][3] + bi.w, 0.f);
      int byte = rowL*128 + (((colb>>3) ^ (rowL&7)) << 4) + ((colb>>2)&1)*8;
      *(half4v*)((char*)hid + byte) = h;
    }
  __syncthreads();

  // ---- GEMM2 ----
  f32x4 acc2[8];
  #pragma unroll
  for (int i = 0; i < 8; ++i){ acc2[i][0]=0.f; acc2[i][1]=0.f; acc2[i][2]=0.f; acc2[i][3]=0.f; }
  #pragma unroll
  for (int s = 0; s < 2; ++s){
    half8 af2[2];
    #pragma unroll
    for (int mf = 0; mf < 2; ++mf){
      int rowL = wave*32 + mf*16 + l15;
      int kc = g + s*4;
      int byte = rowL*128 + ((kc ^ (rowL&7)) << 4);
      af2[mf] = *(const half8*)((const char*)hid + byte);
    }
    #pragma unroll
    for (int nf = 0; nf < 4; ++nf){
      half8 bf2 = *(const half8*)(B2 + (size_t)(nf*16 + l15)*64 + s*32 + g*8);
      #pragma unroll
      for (int mf = 0; mf < 2; ++mf)
        acc2[mf*4+nf] = __builtin_amdgcn_mfma_f32_16x16x32_f16(bf2, af2[mf], acc2[mf*4+nf], 0,0,0);
    }
  }
  // + b2, scatter to CSR position
  #pragma unroll
  for (int mf = 0; mf < 2; ++mf){
    int dstRow = inv[row0 + wave*32 + mf*16 + l15];
    #pragma unroll
    for (int nf = 0; nf < 4; ++nf){
      int colb = nf*16 + g*4;
      float4 bi = ld4(&b2[colb]);
      half4v h;
      h[0] = (f16)(acc2[mf*4+nf][0] + bi.x);
      h[1] = (f16)(acc2[mf*4+nf][1] + bi.y);
      h[2] = (f16)(acc2[mf*4+nf][2] + bi.z);
      h[3] = (f16)(acc2[mf*4+nf][3] + bi.w);
      *(half4v*)(EFh + (size_t)dstRow*64 + colb) = h;
    }
  }
}

// ---------------- MFMA fp16 GEMM (gload_lds + XOR swizzle, 128xBN, BK=32) ---
// C = [A1 | A2] @ Bpk + bias.  Grid (Ncols/BN, ceil(M/128)).
// Swapped-operand MFMA: lane holds C row (base + lane&15), 4 consecutive cols.
// mode 0: +bias; 1: +bias,relu; 2: +bias +ep(f16,ldep) +BN +ELU.
__device__ __forceinline__ float bn_elu(float x, float g, float b, float m, float v){
  float s = g / sqrtf(v + 1e-5f);
  float y = (x - m) * s + b;
  return y > 0.f ? y : expm1f(y);
}

template<int BN>
__global__ __launch_bounds__(256)
void hgemm_kernel(const f16* __restrict__ A1, int lda1, int K1,
                  const f16* __restrict__ A2, int lda2, int K2,
                  const f16* __restrict__ Bpk, int Kp,
                  const float* __restrict__ bias,
                  f16* __restrict__ C, int ldc, int M, int mode,
                  const f16* __restrict__ ep, int ldep,
                  const float* __restrict__ bng, const float* __restrict__ bnb,
                  const float* __restrict__ bnm, const float* __restrict__ bnv,
                  int headOff, size_t pstride, int hcShift)
{
  constexpr int WM = (BN == 128) ? 64 : 32;
  constexpr int MF = WM / 16;
  __shared__ f16 As[128*32];
  __shared__ f16 Bs[BN*32];
  const int tid  = threadIdx.x;
  const int lane = tid & 63;
  const int wave = tid >> 6;
  const int wm   = (BN == 128) ? (wave >> 1) : wave;
  const int wn   = (BN == 128) ? (wave & 1) : 0;
  const int l15  = lane & 15;
  const int cs   = (lane >> 4) ^ ((lane >> 2) & 3);   // fragment-read chunk
  const int csl  = (lane & 3) ^ (lane >> 4);          // staging source chunk
  const int arow = lane >> 2;                         // staging row-in-group

  // XCD-chunked bijective swizzle
  const int nbx = gridDim.x;
  const int nwg = nbx * gridDim.y;
  int bid = blockIdx.y * nbx + blockIdx.x;
  {
    int q = nwg >> 3, r = nwg & 7;
    int xcd = bid & 7, idx = bid >> 3;
    bid = (xcd < r ? xcd * (q + 1) : r * (q + 1) + (xcd - r) * q) + idx;
  }
  const int row0 = (bid / nbx) * 128;
  const int col0 = (bid % nbx) * BN;
  const f16* A1b = headOff ? (A1 + col0) : A1;

  f32x4 acc[MF*4];
  #pragma unroll
  for (int i = 0; i < MF*4; ++i){ acc[i][0]=0.f; acc[i][1]=0.f; acc[i][2]=0.f; acc[i][3]=0.f; }

  for (int k0 = 0; k0 < Kp; k0 += 32) {
    const f16* Ap; int lda, ks;
    if (k0 < K1) { Ap = A1b; lda = lda1; ks = k0; }
    else         { Ap = A2;  lda = lda2; ks = k0 - K1; }
    // stage A: wave covers rows [wave*32, wave*32+32), 2 issues of 16 rows
    #pragma unroll
    for (int t = 0; t < 2; ++t) {
      int r = wave*32 + t*16 + arow;
      gload16(Ap + (size_t)(row0 + r)*lda + ks + csl*8, As + (wave*32 + t*16)*32);
    }
    // stage B
    if (BN == 128) {
      #pragma unroll
      for (int t = 0; t < 2; ++t) {
        int r = wave*32 + t*16 + arow;
        gload16(Bpk + (size_t)(col0 + r)*Kp + k0 + csl*8, Bs + (wave*32 + t*16)*32);
      }
    } else {
      int r = wave*16 + arow;
      gload16(Bpk + (size_t)(col0 + r)*Kp + k0 + csl*8, Bs + wave*16*32);
    }
    __syncthreads();   // drains vmcnt (compiler emits s_waitcnt vmcnt(0))

    half8 af[MF], bf[4];
    #pragma unroll
    for (int mf = 0; mf < MF; ++mf)
      af[mf] = *(const half8*)(As + (wm*WM + mf*16 + l15)*32 + cs*8);
    #pragma unroll
    for (int nf = 0; nf < 4; ++nf)
      bf[nf] = *(const half8*)(Bs + (wn*64 + nf*16 + l15)*32 + cs*8);
    #pragma unroll
    for (int mf = 0; mf < MF; ++mf)
      #pragma unroll
      for (int nf = 0; nf < 4; ++nf)
        acc[mf*4+nf] = __builtin_amdgcn_mfma_f32_16x16x32_f16(bf[nf], af[mf], acc[mf*4+nf], 0,0,0);
    __syncthreads();
  }

  // epilogue (swapped layout): lane -> row = base + l15, cols = colb..colb+3
  #pragma unroll
  for (int mf = 0; mf < MF; ++mf)
    #pragma unroll
    for (int nf = 0; nf < 4; ++nf){
      int row  = row0 + wm*WM + mf*16 + l15;
      int colb = col0 + wn*64 + nf*16 + (lane>>4)*4;
      if (row >= M) continue;
      float4 bi = bias ? ld4(&bias[colb]) : make_float4(0.f,0.f,0.f,0.f);
      float r0 = acc[mf*4+nf][0] + bi.x;
      float r1 = acc[mf*4+nf][1] + bi.y;
      float r2 = acc[mf*4+nf][2] + bi.z;
      float r3 = acc[mf*4+nf][3] + bi.w;
      if (mode == 1){
        r0=fmaxf(r0,0.f); r1=fmaxf(r1,0.f); r2=fmaxf(r2,0.f); r3=fmaxf(r3,0.f);
      } else if (mode == 2){
        half4v e4 = *(const half4v*)(ep + (size_t)row*ldep + colb);
        float4 g4 = ld4(&bng[colb]);
        float4 b4 = ld4(&bnb[colb]);
        float4 m4 = ld4(&bnm[colb]);
        float4 v4 = ld4(&bnv[colb]);
        r0 = bn_elu(r0 + (float)e4[0], g4.x, b4.x, m4.x, v4.x);
        r1 = bn_elu(r1 + (float)e4[1], g4.y, b4.y, m4.y, v4.y);
        r2 = bn_elu(r2 + (float)e4[2], g4.z, b4.z, m4.z, v4.z);
        r3 = bn_elu(r3 + (float)e4[3], g4.w, b4.w, m4.w, v4.w);
      }
      half4v h; h[0]=(f16)r0; h[1]=(f16)r1; h[2]=(f16)r2; h[3]=(f16)r3;
      f16* dstp;
      if (pstride){
        int hc = 1 << hcShift;
        int plane = colb >> hcShift, c2 = colb & (hc - 1);
        dstp = C + (size_t)plane*pstride + (size_t)row*hc + c2;
      } else {
        dstp = C + (size_t)row*ldc + colb;
      }
      *(half4v*)dstp = h;
    }
}

// ---------------- aggregation: online softmax, 2-deep pipelined -------------
// Planes: Q=PROJ, K=PROJ+ps, V=+2ps, QWE=+3ps; each [N,HC] compact.
// att overwrites Q plane row, SE overwrites QWE plane row.
template<int HC>
__global__ __launch_bounds__(256)
void agg16_kernel(const int* __restrict__ rowptr, const int* __restrict__ csr_src,
                  f16* __restrict__ PROJ, size_t ps, const f16* __restrict__ EFh, int nNodes)
{
  int lane = threadIdx.x & 63;
  int wid = (blockIdx.x * blockDim.x + threadIdx.x) >> 6;
  int grp = lane >> 4, l16 = lane & 15;
  int node, ch;
  if (HC == 256) { node = wid;          ch = 4*lane; }
  else           { node = wid*4 + grp;  ch = 4*l16;  }
  if (node >= nNodes) return;
  f16* Qp = PROJ;
  const f16* Kp = PROJ + ps;
  const f16* Vp = PROJ + 2*ps;
  f16* Wp = PROJ + 3*ps;
  half4v qh = *(const half4v*)(Qp + (size_t)node*HC + ch);
  half4v wh = *(const half4v*)(Wp + (size_t)node*HC + ch);
  float q0=qh[0],q1=qh[1],q2=qh[2],q3=qh[3];
  float w0=wh[0],w1=wh[1],w2=wh[2],w3=wh[3];
  int e0 = rowptr[node], e1 = rowptr[node+1];

  float m = -INFINITY, den = 0.f;
  float avx=0.f,avy=0.f,avz=0.f,avw=0.f, aex=0.f,aey=0.f,aez=0.f,aew=0.f;

  half4v kN, vN, eN;
  if (e0 < e1) {
    size_t so = (size_t)csr_src[e0]*HC + ch;
    kN = *(const half4v*)(Kp + so);
    vN = *(const half4v*)(Vp + so);
    eN = *(const half4v*)(EFh + (size_t)e0*64 + 4*l16);
  }
  for (int i = e0; i < e1; ++i) {
    half4v k4 = kN, v4 = vN, e4 = eN;
    if (i + 1 < e1) {
      size_t so = (size_t)csr_src[i+1]*HC + ch;
      kN = *(const half4v*)(Kp + so);
      vN = *(const half4v*)(Vp + so);
      eN = *(const half4v*)(EFh + (size_t)(i+1)*64 + 4*l16);
    }
    float ex=e4[0], ey=e4[1], ez=e4[2], ew=e4[3];
    float p = q0*(float)k4[0] + q1*(float)k4[1] + q2*(float)k4[2] + q3*(float)k4[3]
            + w0*ex + w1*ey + w2*ez + w3*ew;
    p += __shfl_xor(p, 1);
    p += __shfl_xor(p, 2);
    p += __shfl_xor(p, 4);
    p += __shfl_xor(p, 8);
    float alpha = p * 0.125f;       // 1/sqrt(64)
    float mn = fmaxf(m, alpha);
    float sc = __expf(m - mn);      // -inf -> 0 on first edge
    float w  = __expf(alpha - mn);
    den = den*sc + w;
    avx = avx*sc + w*(float)v4[0]; avy = avy*sc + w*(float)v4[1];
    avz = avz*sc + w*(float)v4[2]; avw = avw*sc + w*(float)v4[3];
    aex = aex*sc + w*ex; aey = aey*sc + w*ey;
    aez = aez*sc + w*ez; aew = aew*sc + w*ew;
    m = mn;
  }
  float inv = den > 0.f ? 1.0f/den : 0.f;
  half4v o1, o2;
  o1[0]=(f16)(avx*inv); o1[1]=(f16)(avy*inv); o1[2]=(f16)(avz*inv); o1[3]=(f16)(avw*inv);
  o2[0]=(f16)(aex*inv); o2[1]=(f16)(aey*inv); o2[2]=(f16)(aez*inv); o2[3]=(f16)(aew*inv);
  *(half4v*)(Qp + (size_t)node*HC + ch) = o1;
  *(half4v*)(Wp + (size_t)node*HC + ch) = o2;
}

// ---------------- mean pool (batch sorted, fp16 in) ----------------
__global__ void pool16_kernel(const f16* __restrict__ Hf, const int* __restrict__ batch,
                              float* __restrict__ gsum, int nNodes){
  const int CH = 64;
  int c = threadIdx.x & 63;
  int chunk = blockIdx.x * (blockDim.x >> 6) + (threadIdx.x >> 6);
  int n0 = chunk * CH;
  if (n0 >= nNodes) return;
  int n1 = min(n0 + CH, nNodes);
  float acc = 0.f;
  int g = batch[n0];
  for (int n = n0; n < n1; ++n) {
    int gn = batch[n];
    if (gn != g) { atomicAdd(&gsum[g*64 + c], acc); acc = 0.f; g = gn; }
    acc += (float)Hf[(size_t)n*64 + c];
  }
  atomicAdd(&gsum[g*64 + c], acc);
}

// ---------------- MLP head: weights staged in LDS (fp32) ----------------
__global__ void mlp_kernel(const float* __restrict__ gsum, const int* __restrict__ batch,
                           int nNodes, int G,
                           const float* __restrict__ w1, const float* __restrict__ b1,
                           const float* __restrict__ w2, const float* __restrict__ b2,
                           const float* __restrict__ w3, const float* __restrict__ b3,
                           float* __restrict__ out){
  __shared__ float s_w1[2048], s_w2[512], s_w3[16], s_b1[32], s_b2[16];
  int t = threadIdx.x;
  for (int i = t; i < 2048; i += 128) s_w1[i] = w1[i];
  for (int i = t; i < 512;  i += 128) s_w2[i] = w2[i];
  if (t < 16) s_w3[t] = w3[t];
  if (t < 32) s_b1[t] = b1[t];
  if (t < 16) s_b2[t] = b2[t];
  __syncthreads();
  int g = t;
  if (g >= G) return;
  int lo = 0, hi = nNodes;
  while (lo < hi){ int mid = (lo+hi)>>1; if (batch[mid] < g) lo = mid+1; else hi = mid; }
  int first = lo;
  lo = 0; hi = nNodes;
  while (lo < hi){ int mid = (lo+hi)>>1; if (batch[mid] < g+1) lo = mid+1; else hi = mid; }
  int cnt = lo - first;
  float invc = 1.0f / fmaxf((float)cnt, 1.0f);
  float gm[64];
  #pragma unroll
  for (int c = 0; c < 64; ++c) gm[c] = gsum[g*64 + c] * invc;
  float r1[32];
  #pragma unroll
  for (int j = 0; j < 32; ++j){
    float s = s_b1[j];
    #pragma unroll 8
    for (int c = 0; c < 64; ++c) s = fmaf(gm[c], s_w1[c*32 + j], s);
    r1[j] = fmaxf(s, 0.f);
  }
  float r2[16];
  #pragma unroll
  for (int j = 0; j < 16; ++j){
    float s = s_b2[j];
    #pragma unroll 8
    for (int c = 0; c < 32; ++c) s = fmaf(r1[c], s_w2[c*16 + j], s);
    r2[j] = fmaxf(s, 0.f);
  }
  float s = b3[0];
  #pragma unroll
  for (int c = 0; c < 16; ++c) s = fmaf(r2[c], s_w3[c], s);
  out[g] = s;
}

// ---------------------------------------------------------------------------
template<int BN>
static inline void launch_hgemm(hipStream_t st,
    const f16* A1, int lda1, int K1, const f16* A2, int lda2, int K2,
    const f16* Bpk, int Kp, const float* bias,
    f16* C, int ldc, int M, int Ncols, int mode,
    const f16* ep, int ldep,
    const float* g, const float* b, const float* m, const float* v,
    int headOff = 0, size_t pstride = 0, int hcShift = 0)
{
  dim3 grid(Ncols / BN, (M + 127) / 128, 1);
  hgemm_kernel<BN><<<grid, 256, 0, st>>>(A1, lda1, K1, A2, lda2, K2, Bpk, Kp,
                                         bias, C, ldc, M, mode, ep, ldep, g, b, m, v,
                                         headOff, pstride, hcShift);
}

struct ConvW {
  const float *wq,*bq,*wk,*bk,*wv,*bv,*we,*ws,*bs,*bg,*bb,*bm,*bv_;
};

extern "C" void kernel_launch(void* const* d_in, const int* in_sizes, int n_in,
                              void* d_out, int out_size, void* d_ws, size_t ws_size,
                              hipStream_t stream) {
  (void)n_in;
  const float* x     = (const float*)d_in[0];
  const int*   ei    = (const int*)d_in[1];
  const float* eattr = (const float*)d_in[2];
  const int*   batch = (const int*)d_in[3];
  const float* ee_w1 = (const float*)d_in[4];
  const float* ee_b1 = (const float*)d_in[5];
  const float* ee_w2 = (const float*)d_in[6];
  const float* ee_b2 = (const float*)d_in[7];
  ConvW cw[3];
  {
    int t = 8;
    for (int c = 0; c < 3; ++c){
      cw[c].wq=(const float*)d_in[t++]; cw[c].bq=(const float*)d_in[t++];
      cw[c].wk=(const float*)d_in[t++]; cw[c].bk=(const float*)d_in[t++];
      cw[c].wv=(const float*)d_in[t++]; cw[c].bv=(const float*)d_in[t++];
      cw[c].we=(const float*)d_in[t++]; cw[c].ws=(const float*)d_in[t++]; cw[c].bs=(const float*)d_in[t++];
    }
    for (int c = 0; c < 3; ++c){
      cw[c].bg=(const float*)d_in[t++]; cw[c].bb=(const float*)d_in[t++];
      cw[c].bm=(const float*)d_in[t++]; cw[c].bv_=(const float*)d_in[t++];
    }
  }
  const float* r_w1 = (const float*)d_in[47];
  const float* r_b1 = (const float*)d_in[48];
  const float* r_w2 = (const float*)d_in[49];
  const float* r_b2 = (const float*)d_in[50];
  const float* r_w3 = (const float*)d_in[51];
  const float* r_b3 = (const float*)d_in[52];

  const int N = in_sizes[0] / 64;      // 50000
  const int E = in_sizes[2] / 16;      // 400000 (multiple of 128)
  const int G = out_size;              // 128

  // ---- workspace layout (A-source buffers padded 128 rows for gload) ----
  const size_t NPAD = (size_t)N + 128;
  char* wp = (char*)d_ws;
  f16* HA   = (f16*)wp;            wp += NPAD*256*2;
  f16* HB   = (f16*)wp;            wp += NPAD*256*2;
  f16* PROJ = (f16*)wp;            wp += NPAD*1024*2;
  f16* EFh  = (f16*)wp;            wp += (size_t)E*64*2;
  f16* Bpk  = (f16*)wp;            wp += 534528*2;
  float* biasAll = (float*)wp;     wp += 2304*4;
  float* gsum    = (float*)wp;     wp += 8192*4;
  int* ideg  = (int*)wp;           wp += (size_t)N*4;
  int* icnt  = (int*)wp;           wp += (size_t)N*4;
  int* irow  = (int*)wp;           wp += (size_t)(N+1)*4;
  int* csr_s = (int*)wp;           wp += (size_t)E*4;
  int* inv   = (int*)wp;           wp += (size_t)E*4;
  size_t used = (size_t)(wp - (char*)d_ws);
  if (used > ws_size) {
    leak_kernel<<<(G + 255)/256, 256, 0, stream>>>((float*)d_out, G, (float)(ws_size >> 20));
    return;
  }

  const int* src = ei;
  const int* dst = ei + E;

  // Bpk job offsets
  const int BO_E1 = 0, BO_E2 = 2048, BO_P0 = 6144, BO_P1 = 71680, BO_P2 = 333824;
  const int BO_S0 = 399360, BO_S1 = 432128, BO_S2 = 514048;

  // ---- prep: weights + bias + zero(gsum/ideg/icnt) + cvt16(x) ----
  PrepP P;
  P.ee_w1 = ee_w1; P.ee_w2 = ee_w2;
  for (int c = 0; c < 3; ++c){
    P.wq[c]=cw[c].wq; P.wk[c]=cw[c].wk; P.wv[c]=cw[c].wv; P.we[c]=cw[c].we; P.ws[c]=cw[c].ws;
    P.bq[c]=cw[c].bq; P.bk[c]=cw[c].bk; P.bv[c]=cw[c].bv;
  }
  P.Bpk = Bpk; P.biasAll = biasAll;
  P.zeroP = (int*)gsum; P.nZero = 8192 + 2*N;
  P.x = x; P.XA = HA; P.nXA = N*64;
  {
    long total = 534528 + 2304 + (long)P.nZero + P.nXA;
    prep_kernel<<<(int)((total + 255)/256), 256, 0, stream>>>(P);
  }

  // ---- CSR by dst (+ inv permutation) ----
  hist_kernel<<<(E + 255)/256, 256, 0, stream>>>(dst, ideg, E);
  scan_kernel<<<1, 1024, 0, stream>>>(ideg, irow, N);
  scatter_kernel<<<(E + 255)/256, 256, 0, stream>>>(src, dst, irow, icnt, csr_s, inv, E);

  // ---- fused edge encoder -> EFh (CSR order) ----
  enc_fused_kernel<<<E/128, 256, 0, stream>>>(eattr, Bpk + BO_E1, Bpk + BO_E2,
                                              ee_b1, ee_b2, inv, EFh, E);

  // ================= conv layers =================
  const int BO_P[3] = {BO_P0, BO_P1, BO_P2};
  const int BO_S[3] = {BO_S0, BO_S1, BO_S2};
  const int bOff[3] = {0, 1024, 2048};
  for (int c = 0; c < 3; ++c) {
    const int din = (c == 0) ? 64 : 256;
    const int H   = (c == 2) ? 1 : 4;
    const int hc  = H * 64;
    const int hcShift = (hc == 256) ? 8 : 6;
    const size_t ps = NPAD * (size_t)hc;
    const f16* Xin = (c == 0) ? HA : ((c == 1) ? HB : HA);
    const int  ldx = (c == 0) ? 64 : 256;
    f16* Hout = (c == 1) ? HA : HB;
    const ConvW& W = cw[c];

    // fused projection into planes: [Q|K|V|QWE] each [N,hc]
    launch_hgemm<128>(stream, Xin, ldx, din, nullptr, 0, 0, Bpk + BO_P[c], din,
                      biasAll + bOff[c], PROJ, hc, N, 4*hc, 0, nullptr, 0, 0,0,0,0,
                      0, ps, hcShift);

    // aggregation (att -> Q plane, SE -> QWE plane)
    if (H == 4) agg16_kernel<256><<<(N + 3)/4,  256, 0, stream>>>(irow, csr_s, PROJ, ps, EFh, N);
    else        agg16_kernel<64> <<<(N + 15)/16,256, 0, stream>>>(irow, csr_s, PROJ, ps, EFh, N);

    // post: Hout = BN_ELU( SE_h@we_h + X@ws + bs + att ), Kpp = 64+din
    launch_hgemm<64>(stream, PROJ + 3*ps, hc, 64, Xin, ldx, din, Bpk + BO_S[c], 64 + din,
                     W.bs, Hout, hc, N, hc, 2, PROJ, hc, W.bg, W.bb, W.bm, W.bv_,
                     1, 0, 0);
  }

  // ---- global mean pool + MLP ----
  {
    int chunks = (N + 63) / 64;
    pool16_kernel<<<(chunks + 3)/4, 256, 0, stream>>>(HB, batch, gsum, N);
  }
  mlp_kernel<<<1, 128, 0, stream>>>(gsum, batch, N, G, r_w1, r_b1, r_w2, r_b2, r_w3, r_b3,
                                    (float*)d_out);
}